// Round 10
// baseline (742.741 us; speedup 1.0000x reference)
//
#include <hip/hip_runtime.h>

// GCN 2-layer: N=200000, E=12800000, features 2 -> 16 -> 2.
// R2: rank trick -- aggregate only 2-dim vectors (before W1 / after W2).
// R4/R5: counting-sort by dst bucket + LDS agg; coalesced scatter.
// R6/R9: split-bucket agg, 4/8-deep ILP -> pinned at ~145us: divergent lane
//        gathers cost ~7 cyc/miss of per-CU L1 occupancy (rate limit,
//        insensitive to occupancy & ILP).
// R7/R8: tile experiments. R7's LDS-gather concept was right; its 360us was
//        the per-edge serial run SEARCH + 2 blocks/CU, not staging.
// R10: LDS-gather done right. scatter2 sub-sorts each 1024-dst-group's
//      sub-chunks by 2048-src-tile (coalesced writes, deg fused). agg stages
//      each 16KB tile in LDS and gathers via ds_read using precomputed run
//      tables -- the gather path never touches L1. Est ~10us/CU-pass of LDS
//      work vs the 350K-cycle L1-miss wall.

constexpr int N_NODES = 200000;
constexpr int N_EDGES = 12800000;
constexpr int RANGE_SHIFT = 8;                       // 256 nodes / bucket
constexpr int K_BUCKETS = (N_NODES + 255) / 256;     // 782
constexpr int SORT_BLOCKS = 2048;
constexpr int CHUNK = N_EDGES / SORT_BLOCKS;         // 6250 exactly
constexpr int SCAN_R = SORT_BLOCKS / 256;            // 8
constexpr int G_NODES = 1024;                        // dst-group (4 buckets)
constexpr int N_GROUPS = 196;
constexpr int SUB = 12;                              // sub-chunks per group (<=~5600 edges, CAP 6400)
constexpr int CAP = 6400;
constexpr int TSHIFT = 11;                           // src tile = 2048 nodes
constexpr int T_NODES = 2048;
constexpr int NT = 98;                               // ceil(200000/2048)
constexpr int GP = 3;                                // agg blocks per group

// ---------------- pass-1 sort (R5-proven) ----------------

__global__ __launch_bounds__(256) void hist_kernel(const int* __restrict__ dst,
                                                   unsigned* __restrict__ blockHist) {
    __shared__ unsigned h[K_BUCKETS];
    for (int i = threadIdx.x; i < K_BUCKETS; i += 256) h[i] = 0;
    __syncthreads();
    int base = blockIdx.x * CHUNK;
    for (int e = base + threadIdx.x; e < base + CHUNK; e += 256)
        atomicAdd(&h[((unsigned)dst[e]) >> RANGE_SHIFT], 1u);
    __syncthreads();
    unsigned* row = blockHist + (size_t)blockIdx.x * K_BUCKETS;
    for (int i = threadIdx.x; i < K_BUCKETS; i += 256) row[i] = h[i];
}

__global__ __launch_bounds__(256) void scan_perblock_kernel(unsigned* __restrict__ blockHist,
                                                            unsigned* __restrict__ bucketTotal) {
    int b = blockIdx.x, t = threadIdx.x;
    unsigned v[SCAN_R], run = 0;
#pragma unroll
    for (int j = 0; j < SCAN_R; j++) v[j] = blockHist[(size_t)(SCAN_R * t + j) * K_BUCKETS + b];
#pragma unroll
    for (int j = 0; j < SCAN_R; j++) { unsigned tmp = v[j]; v[j] = run; run += tmp; }
    __shared__ unsigned sh[256];
    sh[t] = run;
    __syncthreads();
    for (int off = 1; off < 256; off <<= 1) {
        unsigned add = (t >= off) ? sh[t - off] : 0u;
        __syncthreads();
        sh[t] += add;
        __syncthreads();
    }
    unsigned excl = sh[t] - run;
#pragma unroll
    for (int j = 0; j < SCAN_R; j++)
        blockHist[(size_t)(SCAN_R * t + j) * K_BUCKETS + b] = excl + v[j];
    if (t == 255) bucketTotal[b] = sh[255];
}

__global__ __launch_bounds__(1024) void scan_buckets_kernel(const unsigned* __restrict__ bucketTotal,
                                                            unsigned* __restrict__ bucketStart) {
    __shared__ unsigned sh[1024];
    int t = threadIdx.x;
    unsigned v = (t < K_BUCKETS) ? bucketTotal[t] : 0u;
    sh[t] = v;
    __syncthreads();
    for (int off = 1; off < 1024; off <<= 1) {
        unsigned add = (t >= off) ? sh[t - off] : 0u;
        __syncthreads();
        sh[t] += add;
        __syncthreads();
    }
    if (t < K_BUCKETS) bucketStart[t] = sh[t] - v;
    if (t == K_BUCKETS - 1) bucketStart[K_BUCKETS] = sh[t];
}

// Packed 4B entry: src (18b) | group-local dst (10b) << 18.
__global__ __launch_bounds__(256) void scatter_kernel(const int* __restrict__ src,
                                                      const int* __restrict__ dst,
                                                      const unsigned* __restrict__ blockHist,
                                                      const unsigned* __restrict__ bucketStart,
                                                      unsigned* __restrict__ sorted) {
    __shared__ unsigned s_hist[K_BUCKETS];
    __shared__ unsigned s_cur[K_BUCKETS];
    __shared__ int      s_base[K_BUCKETS];
    __shared__ unsigned ssum[256];
    __shared__ unsigned ent[CHUNK];
    __shared__ unsigned short bk[CHUNK];

    int t = threadIdx.x;
    int base = blockIdx.x * CHUNK;
    for (int i = t; i < K_BUCKETS; i += 256) s_hist[i] = 0;
    __syncthreads();

    for (int e = base + t; e < base + CHUNK; e += 256)
        atomicAdd(&s_hist[((unsigned)dst[e]) >> RANGE_SHIFT], 1u);
    __syncthreads();

    unsigned v[4], run = 0;
#pragma unroll
    for (int j = 0; j < 4; j++) {
        int idx = 4 * t + j;
        v[j] = (idx < K_BUCKETS) ? s_hist[idx] : 0u;
    }
#pragma unroll
    for (int j = 0; j < 4; j++) { unsigned tmp = v[j]; v[j] = run; run += tmp; }
    ssum[t] = run;
    __syncthreads();
    for (int off = 1; off < 256; off <<= 1) {
        unsigned add = (t >= off) ? ssum[t - off] : 0u;
        __syncthreads();
        ssum[t] += add;
        __syncthreads();
    }
    unsigned excl = ssum[t] - run;
    const unsigned* row = blockHist + (size_t)blockIdx.x * K_BUCKETS;
#pragma unroll
    for (int j = 0; j < 4; j++) {
        int idx = 4 * t + j;
        if (idx < K_BUCKETS) {
            unsigned st = excl + v[j];
            s_cur[idx] = st;
            s_base[idx] = (int)(bucketStart[idx] + row[idx]) - (int)st;
        }
    }
    __syncthreads();

    for (int e = base + t; e < base + CHUNK; e += 256) {
        unsigned d = (unsigned)dst[e];
        unsigned s = (unsigned)src[e];
        unsigned b = d >> RANGE_SHIFT;
        unsigned lpos = atomicAdd(&s_cur[b], 1u);
        ent[lpos] = s | ((d & 1023u) << 18);     // 10-bit group-local dst
        bk[lpos] = (unsigned short)b;
    }
    __syncthreads();

    for (int i = t; i < CHUNK; i += 256) {
        unsigned b = bk[i];
        sorted[s_base[b] + i] = ent[i];
    }
}

// ---------------- pass-2: sub-sort by src-tile, degree fused ----------------
// Grid: N_GROUPS*SUB. Each block owns sub-chunk [c0,c1) of its group's run.
// Two coalesced reads; LDS permute; coalesced linear write-back (in-place,
// block-exclusive range, reads drained before writes by __syncthreads).
__global__ __launch_bounds__(256) void scatter2_kernel(unsigned* __restrict__ sorted,
                                                       const unsigned* __restrict__ bucketStart,
                                                       unsigned short* __restrict__ lstart,
                                                       unsigned short* __restrict__ pcnt) {
    __shared__ unsigned ent2[CAP];
    __shared__ unsigned cnt[G_NODES];
    __shared__ unsigned h[NT], cur[NT];
    int t = threadIdx.x;
    int g = blockIdx.x / SUB, s = blockIdx.x % SUB;
    int gS = bucketStart[4 * g];
    int gE = bucketStart[min(4 * g + 4, K_BUCKETS)];
    int len = gE - gS;
    int c0 = gS + (int)((long long)len * s / SUB);
    int c1 = gS + (int)((long long)len * (s + 1) / SUB);
    int n = c1 - c0;
    for (int i = t; i < G_NODES; i += 256) cnt[i] = 0;
    if (t < NT) h[t] = 0;
    __syncthreads();
    // pass A: histogram by src-tile + degree count
    for (int i = t; i < n; i += 256) {
        unsigned w = sorted[c0 + i];
        atomicAdd(&h[(w & 0x3FFFFu) >> TSHIFT], 1u);
        atomicAdd(&cnt[w >> 18], 1u);
    }
    __syncthreads();
    if (t == 0) {
        unsigned r = 0;
        for (int j = 0; j < NT; j++) { unsigned c = h[j]; h[j] = r; cur[j] = r; r += c; }
    }
    __syncthreads();
    int lb = blockIdx.x * (NT + 1);
    if (t < NT) lstart[lb + t] = (unsigned short)h[t];
    if (t == 0) lstart[lb + NT] = (unsigned short)n;
    // pass B: re-read, permute into LDS
    for (int i = t; i < n; i += 256) {
        unsigned w = sorted[c0 + i];
        unsigned r = atomicAdd(&cur[(w & 0x3FFFFu) >> TSHIFT], 1u);
        ent2[r] = w;
    }
    __syncthreads();   // all reads of [c0,c1) done before any write
    for (int i = t; i < n; i += 256) sorted[c0 + i] = ent2[i];
    for (int i = t; i < G_NODES; i += 256)
        pcnt[(size_t)blockIdx.x * G_NODES + i] = (unsigned short)cnt[i];
}

// ---------------- GCN phase ----------------

__global__ __launch_bounds__(256) void node1_kernel(const float2* __restrict__ x,
                                                    const unsigned short* __restrict__ pcnt,
                                                    float* __restrict__ dinv,
                                                    float2* __restrict__ u) {
    int i = blockIdx.x * 256 + threadIdx.x;
    if (i >= N_NODES) return;
    int g = i >> 10, l = i & 1023;
    unsigned c = 1;  // +1 self loop
#pragma unroll
    for (int s = 0; s < SUB; s++) c += pcnt[(size_t)(g * SUB + s) * G_NODES + l];
    float di = rsqrtf((float)c);
    dinv[i] = di;
    float2 xi = x[i];
    u[i] = make_float2(di * xi.x, di * xi.y);
}

// Block (g,p): tiles {p, p+GP, ...}. Stage 16KB tile in LDS (coalesced
// float4), gather via ds_read using run table (no search), LDS acc[1024].
__global__ __launch_bounds__(256) void agg_tile_kernel(const unsigned* __restrict__ sorted,
                                                       const unsigned* __restrict__ bucketStart,
                                                       const unsigned short* __restrict__ lstart,
                                                       const float2* __restrict__ table,
                                                       float2* __restrict__ part) {
    __shared__ float2 tileBuf[T_NODES];                 // 16 KB
    __shared__ float accX[G_NODES], accY[G_NODES];      // 8 KB
    __shared__ int subC0[SUB];
    __shared__ int runS[SUB], runL[SUB];
    int t = threadIdx.x;
    int g = blockIdx.x / GP, p = blockIdx.x % GP;
    int gS = bucketStart[4 * g];
    int gE = bucketStart[min(4 * g + 4, K_BUCKETS)];
    int len = gE - gS;
    for (int i = t; i < G_NODES; i += 256) { accX[i] = 0.f; accY[i] = 0.f; }
    if (t < SUB) subC0[t] = gS + (int)((long long)len * t / SUB);
    for (int tile = p; tile < NT; tile += GP) {
        __syncthreads();   // prev iter done with tileBuf/runS; init visible
        int base = tile << TSHIFT;
        int nf4 = (min(T_NODES, N_NODES - base) + 1) >> 1;
        const float4* s4 = (const float4*)(table + base);
        float4* d4 = (float4*)tileBuf;
        for (int j = t; j < nf4; j += 256) d4[j] = s4[j];
        if (t < SUB) {
            int lb = (g * SUB + t) * (NT + 1);
            int st = lstart[lb + tile], en = lstart[lb + tile + 1];
            runS[t] = subC0[t] + st;
            runL[t] = en - st;
        }
        __syncthreads();
        int wid = t >> 6, lane = t & 63;
        for (int r = wid; r < SUB; r += 4) {
            int st = runS[r], L = runL[r];
            for (int k = lane; k < L; k += 64) {
                unsigned w = sorted[st + k];
                float2 v = tileBuf[w & (T_NODES - 1)];
                unsigned l = w >> 18;
                atomicAdd(&accX[l], v.x);
                atomicAdd(&accY[l], v.y);
            }
        }
    }
    __syncthreads();
    float2* po = part + (size_t)blockIdx.x * G_NODES;
    for (int i = t; i < G_NODES; i += 256) po[i] = make_float2(accX[i], accY[i]);
}

__global__ __launch_bounds__(256) void node2_kernel(const float2* __restrict__ u,
                                                    const float2* __restrict__ part,
                                                    const float* __restrict__ W1,
                                                    const float* __restrict__ b1,
                                                    const float* __restrict__ W2,
                                                    const float* __restrict__ dinv,
                                                    float2* __restrict__ g2) {
    int i = blockIdx.x * 256 + threadIdx.x;
    if (i >= N_NODES) return;
    int g = i >> 10, l = i & 1023;
    float ax = 0.f, ay = 0.f;
#pragma unroll
    for (int p = 0; p < GP; p++) {
        float2 v = part[(size_t)(g * GP + p) * G_NODES + l];
        ax += v.x; ay += v.y;
    }
    float di = dinv[i];
    float2 uu = u[i];
    float c0 = di * (ax + uu.x);
    float c1 = di * (ay + uu.y);
    float a0 = 0.f, a1 = 0.f;
#pragma unroll
    for (int f = 0; f < 16; f++) {
        float o = fmaxf(c0 * W1[f] + c1 * W1[16 + f] + b1[f], 0.f);  // W1 (2,16)
        a0 += o * W2[2 * f];                                         // W2 (16,2)
        a1 += o * W2[2 * f + 1];
    }
    g2[i] = make_float2(di * a0, di * a1);
}

__global__ __launch_bounds__(256) void node3_kernel(const float2* __restrict__ g2,
                                                    const float2* __restrict__ part,
                                                    const float* __restrict__ b2,
                                                    const float* __restrict__ dinv,
                                                    float2* __restrict__ out) {
    int i = blockIdx.x * 256 + threadIdx.x;
    if (i >= N_NODES) return;
    int g = i >> 10, l = i & 1023;
    float ax = 0.f, ay = 0.f;
#pragma unroll
    for (int p = 0; p < GP; p++) {
        float2 v = part[(size_t)(g * GP + p) * G_NODES + l];
        ax += v.x; ay += v.y;
    }
    float di = dinv[i];
    float2 gg = g2[i];
    out[i] = make_float2(di * (ax + gg.x) + b2[0],
                         di * (ay + gg.y) + b2[1]);
}

// ---------------- fallback path (R2-style, 8 MB ws) ----------------

__global__ __launch_bounds__(256) void fb_deg(const int* __restrict__ dst, int* __restrict__ degi) {
    int e = blockIdx.x * 256 + threadIdx.x;
    if (e < N_EDGES) atomicAdd(&degi[dst[e]], 1);
}
__global__ __launch_bounds__(256) void fb_node1(const float* __restrict__ x, const int* __restrict__ degi,
                                                float* __restrict__ dinv, float2* __restrict__ u) {
    int i = blockIdx.x * 256 + threadIdx.x;
    if (i >= N_NODES) return;
    float di = rsqrtf((float)(degi[i] + 1));
    dinv[i] = di;
    float2 xi = ((const float2*)x)[i];
    u[i] = make_float2(di * xi.x, di * xi.y);
}
__global__ __launch_bounds__(256) void fb_agg(const int* __restrict__ src, const int* __restrict__ dst,
                                              const float2* __restrict__ table, float* __restrict__ acc) {
    int e = blockIdx.x * 256 + threadIdx.x;
    if (e >= N_EDGES) return;
    float2 v = table[src[e]];
    size_t d = dst[e];
    unsafeAtomicAdd(&acc[2 * d], v.x);
    unsafeAtomicAdd(&acc[2 * d + 1], v.y);
}
__global__ __launch_bounds__(256) void fb_node2(const float2* __restrict__ u, const float2* __restrict__ A1,
                                                const float* __restrict__ W1, const float* __restrict__ b1,
                                                const float* __restrict__ W2, const float* __restrict__ dinv,
                                                float2* __restrict__ g2) {
    int i = blockIdx.x * 256 + threadIdx.x;
    if (i >= N_NODES) return;
    float di = dinv[i];
    float2 a = A1[i], uu = u[i];
    float c0 = di * (a.x + uu.x), c1 = di * (a.y + uu.y);
    float a0 = 0.f, a1 = 0.f;
#pragma unroll
    for (int f = 0; f < 16; f++) {
        float o = fmaxf(c0 * W1[f] + c1 * W1[16 + f] + b1[f], 0.f);
        a0 += o * W2[2 * f];
        a1 += o * W2[2 * f + 1];
    }
    g2[i] = make_float2(di * a0, di * a1);
}
__global__ __launch_bounds__(256) void fb_node3(const float2* __restrict__ g2, const float2* __restrict__ A2,
                                                const float* __restrict__ b2, const float* __restrict__ dinv,
                                                float2* __restrict__ out) {
    int i = blockIdx.x * 256 + threadIdx.x;
    if (i >= N_NODES) return;
    float di = dinv[i];
    float2 a = A2[i], g = g2[i];
    out[i] = make_float2(di * (a.x + g.x) + b2[0], di * (a.y + g.y) + b2[1]);
}

// ---------------- launcher ----------------

extern "C" void kernel_launch(void* const* d_in, const int* in_sizes, int n_in,
                              void* d_out, int out_size, void* d_ws, size_t ws_size,
                              hipStream_t stream) {
    const float* x  = (const float*)d_in[0];
    const float* W1 = (const float*)d_in[1];
    const float* b1 = (const float*)d_in[2];
    const float* W2 = (const float*)d_in[3];
    const float* b2 = (const float*)d_in[4];
    const int* ei   = (const int*)d_in[5];   // (2,E): row 0 = src, row 1 = dst
    const int* src = ei;
    const int* dst = ei + N_EDGES;
    float2* out = (float2*)d_out;

    // ws layout (4B words), byte-identical total to R6/R9's proven 61.6 MB:
    //   sorted [E] = 12,800,000
    //   region [1,601,536] time-multiplexed:
    //     blockHist u32 (hist..scatter1):            1,601,536 words
    //     lstart u16 [2352*99]  = 116,424 words      (scatter2 .. agg2)
    //     pcnt  u16 [2352*1024] = 1,204,224 words at +116,424 (scatter2..node1)
    //     part float2 [588*1024] = 1,204,224 words at +116,424 (agg1..node3;
    //       aliases pcnt -- pcnt dead after node1, agg1 runs after node1)
    //     116,424 + 1,204,224 = 1,320,648 <= 1,601,536 ok
    //   bucketTotal [784]  bucketStart [784]
    //   dinv [N]  u [2N]  g2 [2N]   (u offset 16B-aligned for float4 staging)
    const size_t REGION = 1601536;
    const size_t need = ((size_t)N_EDGES + REGION + 784 + 784
                         + N_NODES + 2 * (size_t)N_NODES + 2 * (size_t)N_NODES) * 4;

    if (ws_size >= need) {
        unsigned* sorted      = (unsigned*)d_ws;
        unsigned* region      = sorted + N_EDGES;
        unsigned* blockHist   = region;
        unsigned short* lstart = (unsigned short*)region;
        unsigned short* pcnt   = (unsigned short*)(region + 116424);
        float2*   part        = (float2*)(region + 116424);
        unsigned* bucketTotal = region + REGION;
        unsigned* bucketStart = bucketTotal + 784;
        float*    dinv        = (float*)(bucketStart + 784);
        float2*   u           = (float2*)(dinv + N_NODES);
        float2*   g2          = u + N_NODES;

        constexpr int NB = (N_NODES + 255) / 256;
        hist_kernel<<<SORT_BLOCKS, 256, 0, stream>>>(dst, blockHist);
        scan_perblock_kernel<<<K_BUCKETS, 256, 0, stream>>>(blockHist, bucketTotal);
        scan_buckets_kernel<<<1, 1024, 0, stream>>>(bucketTotal, bucketStart);
        scatter_kernel<<<SORT_BLOCKS, 256, 0, stream>>>(src, dst, blockHist, bucketStart, sorted);
        scatter2_kernel<<<N_GROUPS * SUB, 256, 0, stream>>>(sorted, bucketStart, lstart, pcnt);
        node1_kernel<<<NB, 256, 0, stream>>>((const float2*)x, pcnt, dinv, u);
        agg_tile_kernel<<<N_GROUPS * GP, 256, 0, stream>>>(sorted, bucketStart, lstart, u, part);
        node2_kernel<<<NB, 256, 0, stream>>>(u, part, W1, b1, W2, dinv, g2);
        agg_tile_kernel<<<N_GROUPS * GP, 256, 0, stream>>>(sorted, bucketStart, lstart, g2, part);
        node3_kernel<<<NB, 256, 0, stream>>>(g2, part, b2, dinv, out);
    } else {
        // R2-style fallback (8 MB ws): global atomics, ~3.1 ms.
        float* ws = (float*)d_ws;
        int*   degi = (int*)ws;
        float* A1   = ws + N_NODES;
        float* A2   = A1 + 2 * (size_t)N_NODES;
        float* dinvF = A2 + 2 * (size_t)N_NODES;
        float2* uF  = (float2*)(dinvF + N_NODES);
        float2* g2F = uF + N_NODES;
        constexpr int EB = (N_EDGES + 255) / 256;
        constexpr int NB = (N_NODES + 255) / 256;
        hipMemsetAsync(degi, 0, 5 * (size_t)N_NODES * sizeof(float), stream);
        fb_deg<<<EB, 256, 0, stream>>>(dst, degi);
        fb_node1<<<NB, 256, 0, stream>>>(x, degi, dinvF, uF);
        fb_agg<<<EB, 256, 0, stream>>>(src, dst, uF, A1);
        fb_node2<<<NB, 256, 0, stream>>>(uF, (const float2*)A1, W1, b1, W2, dinvF, g2F);
        fb_agg<<<EB, 256, 0, stream>>>(src, dst, g2F, A2);
        fb_node3<<<NB, 256, 0, stream>>>(g2F, (const float2*)A2, b2, dinvF, out);
    }
}